// Round 3
// baseline (337.038 us; speedup 1.0000x reference)
//
#include <hip/hip_runtime.h>
#include <hip/hip_bf16.h>
#include <stdint.h>

// LoRA int8-dequant linear, MI355X/gfx950.
//   Xcat[8192][4160] = [ bf16(x) | bf16(x @ A^T) ]
//   Wcat[4096][4160] = [ bf16(q*scale) | bf16(2*B) ]
//   out = Xcat @ Wcat^T   (fp32 out, fp32 accum)
// Main GEMM: 256x256 tile, BK=64, 8 waves, 4-phase/K-tile, balanced 8/8/8/0
// ds_read distribution, counted vmcnt(4), T2 LDS swizzle, T5 setprio.

typedef __bf16 bf16x8 __attribute__((ext_vector_type(8)));
typedef float f32x4 __attribute__((ext_vector_type(4)));

#define DIN   4096
#define DOUT  4096
#define MTOT  8192
#define RNK   64
#define LDK   4160          // DIN + RNK
#define PITCH 8320          // LDK * 2 bytes
#define NT    65            // K-tiles of 64

__device__ inline void gload_lds16(const void* g, void* l) {
  __builtin_amdgcn_global_load_lds((const __attribute__((address_space(1))) void*)g,
                                   (__attribute__((address_space(3))) void*)l,
                                   16, 0, 0);
}

// ---- x (fp32) -> Xcat[:, 0:4096] bf16 ----
__global__ void cvt_x_kernel(const float* __restrict__ x, __bf16* __restrict__ Xcat) {
  int i = blockIdx.x * blockDim.x + threadIdx.x;
  int row = i >> 10;
  int c4 = (i & 1023) << 2;
  float4 v = *(const float4*)(x + (size_t)row * DIN + c4);
  union { __bf16 h[4]; uint64_t u; } p;
  p.h[0] = (__bf16)v.x; p.h[1] = (__bf16)v.y;
  p.h[2] = (__bf16)v.z; p.h[3] = (__bf16)v.w;
  *(uint64_t*)(Xcat + (size_t)row * LDK + c4) = p.u;
}

// ---- qweight * scale[row] -> Wcat[:, 0:4096] bf16 ----
__global__ void cvt_w_kernel(const int* __restrict__ q, const float* __restrict__ scale,
                             __bf16* __restrict__ Wcat) {
  int i = blockIdx.x * blockDim.x + threadIdx.x;
  int row = i >> 10;
  int c4 = (i & 1023) << 2;
  int4 v = *(const int4*)(q + (size_t)row * DIN + c4);
  float s = scale[row];
  union { __bf16 h[4]; uint64_t u; } p;
  p.h[0] = (__bf16)((float)v.x * s); p.h[1] = (__bf16)((float)v.y * s);
  p.h[2] = (__bf16)((float)v.z * s); p.h[3] = (__bf16)((float)v.w * s);
  *(uint64_t*)(Wcat + (size_t)row * LDK + c4) = p.u;
}

// ---- lora_A -> Abf; 2*lora_B -> Wcat[:, 4096:4160] ----
__global__ void cvt_ab_kernel(const float* __restrict__ A, const float* __restrict__ B,
                              __bf16* __restrict__ Abf, __bf16* __restrict__ Wcat) {
  int i = blockIdx.x * blockDim.x + threadIdx.x;
  {
    int row = i >> 10;
    int c4 = (i & 1023) << 2;
    float4 v = *(const float4*)(A + (size_t)row * DIN + c4);
    union { __bf16 h[4]; uint64_t u; } p;
    p.h[0] = (__bf16)v.x; p.h[1] = (__bf16)v.y;
    p.h[2] = (__bf16)v.z; p.h[3] = (__bf16)v.w;
    *(uint64_t*)(Abf + (size_t)row * DIN + c4) = p.u;
  }
  {
    int row = i >> 4;
    int r4 = (i & 15) << 2;
    float4 v = *(const float4*)(B + (size_t)row * RNK + r4);
    union { __bf16 h[4]; uint64_t u; } p;
    p.h[0] = (__bf16)(2.0f * v.x); p.h[1] = (__bf16)(2.0f * v.y);
    p.h[2] = (__bf16)(2.0f * v.z); p.h[3] = (__bf16)(2.0f * v.w);
    *(uint64_t*)(Wcat + (size_t)row * LDK + DIN + r4) = p.u;
  }
}

// ---- xa = Xcat[:, :4096] @ Abf^T -> bf16 -> Xcat[:, 4096:4160] ----
__global__ __launch_bounds__(128) void lora_xa_kernel(const __bf16* __restrict__ Abf,
                                                      __bf16* Xcat) {
  int wid = threadIdx.x >> 6, lane = threadIdx.x & 63;
  int rowbase = blockIdx.x * 32 + wid * 16;
  f32x4 acc[4] = {};
  const __bf16* xrow = Xcat + (size_t)(rowbase + (lane & 15)) * LDK + ((lane >> 4) * 8);
  for (int k0 = 0; k0 < DIN; k0 += 32) {
    bf16x8 af = *(const bf16x8*)(xrow + k0);
#pragma unroll
    for (int ni = 0; ni < 4; ++ni) {
      bf16x8 bfv = *(const bf16x8*)(Abf + (size_t)(ni * 16 + (lane & 15)) * DIN + k0 + (lane >> 4) * 8);
      acc[ni] = __builtin_amdgcn_mfma_f32_16x16x32_bf16(af, bfv, acc[ni], 0, 0, 0);
    }
  }
#pragma unroll
  for (int ni = 0; ni < 4; ++ni)
#pragma unroll
    for (int j = 0; j < 4; ++j) {
      int row = rowbase + (lane >> 4) * 4 + j;
      int col = ni * 16 + (lane & 15);
      Xcat[(size_t)row * LDK + DIN + col] = (__bf16)acc[ni][j];
    }
}

// ==== main GEMM: 256x256 tile, 8 waves, balanced 4-phase/K-tile pipeline ====
// LDS (128 KiB dynamic): buf[2] x { A0, A1, B0, B1 } x 16 KiB halves.
// Half = 128 rows x 64 cols bf16, row r at bytes r*128 + (c ^ ((r&7)<<4)).
// Staged linearly by global_load_lds with inverse-swizzled per-lane SOURCE.
// Tile kt (cur=kt&1), cluster = one ks x one mi-half x all ni (16 MFMA):
//   ph0: read a(lo,ks0)+b(*,ks0) [8]; stage B1(kt+1)->buf^1; MFMA(ks0,lo)
//   ph1: read a(lo,ks1)+b(*,ks1) [8]; stage A1(kt+1)->buf^1; MFMA(ks1,lo)
//   ph2: read a(hi,ks0)+a(hi,ks1) [8]; stage B0(kt+2)->buf;  MFMA(ks0,hi); lgkm drain
//   ph3: stage A0(kt+2)->buf; MFMA(ks1,hi); vmcnt(4)
// Slot safety: B-slot reads consumed by ph1 < B0 stage(ph2); A-slot reads
// drained by ph2-end lgkmcnt(0) < A0 stage(ph3); A1/B1 overwrites are in the
// other buffer or >=2 barriers after last read. vmcnt(4) leaves only kt+2's
// B0/A0 in flight => all of kt+1's halves landed at tile end.
__global__ __launch_bounds__(512, 2) void gemm8_kernel(const __bf16* __restrict__ Xc,
                                                       const __bf16* __restrict__ Wc,
                                                       float* __restrict__ out) {
  extern __shared__ char smem[];
  const int tid = threadIdx.x;
  const int lane = tid & 63;
  const int w = tid >> 6;        // wave 0..7
  const int wr = w >> 2;         // 0..1 -> rows wr*128
  const int wc = w & 3;          // 0..3 -> cols wc*64

  // bijective XCD swizzle (nwg=512, 512%8==0)
  const int swz = (blockIdx.x & 7) * 64 + (blockIdx.x >> 3);
  const int bx = swz & 15;       // N tile 0..15
  const int by = swz >> 4;       // M tile 0..31
  const size_t bm = (size_t)by * 256, bn = (size_t)bx * 256;

  const char* Ab = (const char*)Xc;
  const char* Bb = (const char*)Wc;

  // staging lane constants: lane covers local row (chunk*8 + lane>>3), 16B col (lane&7)
  const int sl_row = lane >> 3;
  const int sl_col = 16 * ((lane & 7) ^ (lane >> 3));   // inverse-swizzled source col

  // read-side swizzled col byte offsets for ks=0/1
  const int cx0 = (((lane >> 4) << 4)) ^ ((lane & 7) << 4);
  const int cx1 = (64 | ((lane >> 4) << 4)) ^ ((lane & 7) << 4);

  auto STAGE = [&](int st, int buf, int isB, int h) {
    const char* gb = isB ? Bb : Ab;
    const size_t r0 = (isB ? bn : bm) + (size_t)h * 128;
    char* d0 = smem + buf * 65536 + isB * 32768 + h * 16384 + (w * 2) * 1024 + lane * 16;
#pragma unroll
    for (int s = 0; s < 2; ++s) {
      const int rl = (w * 2 + s) * 8 + sl_row;
      gload_lds16(gb + (r0 + rl) * PITCH + (size_t)st * 128 + sl_col, d0 + s * 1024);
    }
  };

  bf16x8 alo[4], ahi[4][2], b[4][2];
  f32x4 acc[8][4] = {};

  // ---- prologue: tile0 all 4 halves, then tile1's {B0, A0}; vmcnt(4) -> t0 landed ----
  STAGE(0, 0, 0, 0); STAGE(0, 0, 0, 1); STAGE(0, 0, 1, 0); STAGE(0, 0, 1, 1);
  STAGE(1, 1, 1, 0); STAGE(1, 1, 0, 0);
  asm volatile("s_waitcnt vmcnt(4)" ::: "memory");
  __builtin_amdgcn_s_barrier();

  for (int kt = 0; kt < NT; ++kt) {
    const int cur = kt & 1;
    const int st1 = (kt + 1 < NT) ? kt + 1 : NT - 1;   // clamped dummy keeps pipeline uniform
    const int st2 = (kt + 2 < NT) ? kt + 2 : NT - 1;
    const int abase = cur * 65536 + wr * 16384 + (lane & 15) * 128;
    const int bbase = cur * 65536 + 32768 + (wc >> 1) * 16384 + ((wc & 1) * 64 + (lane & 15)) * 128;

    // ---------- phase 0: (ks0, mi-lo) ----------
#pragma unroll
    for (int mi = 0; mi < 4; ++mi)
      alo[mi] = *(const bf16x8*)(smem + abase + mi * 2048 + cx0);
#pragma unroll
    for (int ni = 0; ni < 4; ++ni)
      b[ni][0] = *(const bf16x8*)(smem + bbase + ni * 2048 + cx0);
    STAGE(st1, cur ^ 1, 1, 1);
    __builtin_amdgcn_s_barrier();
    __builtin_amdgcn_s_setprio(1);
#pragma unroll
    for (int mi = 0; mi < 4; ++mi)
#pragma unroll
      for (int ni = 0; ni < 4; ++ni)
        acc[mi][ni] = __builtin_amdgcn_mfma_f32_16x16x32_bf16(alo[mi], b[ni][0], acc[mi][ni], 0, 0, 0);
    __builtin_amdgcn_s_setprio(0);
    __builtin_amdgcn_s_barrier();

    // ---------- phase 1: (ks1, mi-lo) ----------
#pragma unroll
    for (int mi = 0; mi < 4; ++mi)
      alo[mi] = *(const bf16x8*)(smem + abase + mi * 2048 + cx1);
#pragma unroll
    for (int ni = 0; ni < 4; ++ni)
      b[ni][1] = *(const bf16x8*)(smem + bbase + ni * 2048 + cx1);
    STAGE(st1, cur ^ 1, 0, 1);
    __builtin_amdgcn_s_barrier();
    __builtin_amdgcn_s_setprio(1);
#pragma unroll
    for (int mi = 0; mi < 4; ++mi)
#pragma unroll
      for (int ni = 0; ni < 4; ++ni)
        acc[mi][ni] = __builtin_amdgcn_mfma_f32_16x16x32_bf16(alo[mi], b[ni][1], acc[mi][ni], 0, 0, 0);
    __builtin_amdgcn_s_setprio(0);
    __builtin_amdgcn_s_barrier();

    // ---------- phase 2: (ks0, mi-hi) ----------
#pragma unroll
    for (int mi = 0; mi < 4; ++mi) {
      ahi[mi][0] = *(const bf16x8*)(smem + abase + 8192 + mi * 2048 + cx0);
      ahi[mi][1] = *(const bf16x8*)(smem + abase + 8192 + mi * 2048 + cx1);
    }
    STAGE(st2, cur, 1, 0);
    __builtin_amdgcn_s_barrier();
    __builtin_amdgcn_s_setprio(1);
#pragma unroll
    for (int mi = 0; mi < 4; ++mi)
#pragma unroll
      for (int ni = 0; ni < 4; ++ni)
        acc[4 + mi][ni] = __builtin_amdgcn_mfma_f32_16x16x32_bf16(ahi[mi][0], b[ni][0], acc[4 + mi][ni], 0, 0, 0);
    __builtin_amdgcn_s_setprio(0);
    asm volatile("s_waitcnt lgkmcnt(0)" ::: "memory");   // drain ahi[*][1] before A0 overwrite
    __builtin_amdgcn_s_barrier();

    // ---------- phase 3: (ks1, mi-hi) ----------
    STAGE(st2, cur, 0, 0);
    __builtin_amdgcn_s_barrier();
    __builtin_amdgcn_s_setprio(1);
#pragma unroll
    for (int mi = 0; mi < 4; ++mi)
#pragma unroll
      for (int ni = 0; ni < 4; ++ni)
        acc[4 + mi][ni] = __builtin_amdgcn_mfma_f32_16x16x32_bf16(ahi[mi][1], b[ni][1], acc[4 + mi][ni], 0, 0, 0);
    __builtin_amdgcn_s_setprio(0);
    asm volatile("s_waitcnt vmcnt(4)" ::: "memory");     // only kt+2's B0/A0 stay in flight
    __builtin_amdgcn_s_barrier();
  }

  // ---- epilogue: C write ----
#pragma unroll
  for (int mi = 0; mi < 8; ++mi)
#pragma unroll
    for (int ni = 0; ni < 4; ++ni) {
      const size_t row = bm + wr * 128 + mi * 16 + (lane >> 4) * 4;
      const size_t col = bn + wc * 64 + ni * 16 + (lane & 15);
#pragma unroll
      for (int j = 0; j < 4; ++j)
        out[(row + j) * DOUT + col] = acc[mi][ni][j];
    }
}

extern "C" void kernel_launch(void* const* d_in, const int* in_sizes, int n_in,
                              void* d_out, int out_size, void* d_ws, size_t ws_size,
                              hipStream_t stream) {
  const float* x = (const float*)d_in[0];
  const int* qw = (const int*)d_in[1];
  const float* scale = (const float*)d_in[2];
  const float* lA = (const float*)d_in[3];
  const float* lB = (const float*)d_in[4];
  float* out = (float*)d_out;

  char* ws = (char*)d_ws;
  __bf16* Xcat = (__bf16*)ws;
  __bf16* Wcat = (__bf16*)(ws + (size_t)MTOT * LDK * 2);
  __bf16* Abf = (__bf16*)(ws + (size_t)MTOT * LDK * 2 + (size_t)DOUT * LDK * 2);

  hipFuncSetAttribute((const void*)gemm8_kernel,
                      hipFuncAttributeMaxDynamicSharedMemorySize, 131072);

  cvt_x_kernel<<<MTOT * (DIN / 4) / 256, 256, 0, stream>>>(x, Xcat);
  cvt_w_kernel<<<DOUT * (DIN / 4) / 256, 256, 0, stream>>>(qw, scale, Wcat);
  cvt_ab_kernel<<<RNK * (DIN / 4) / 256, 256, 0, stream>>>(lA, lB, Abf, Wcat);
  lora_xa_kernel<<<MTOT / 32, 128, 0, stream>>>(Abf, Xcat);
  gemm8_kernel<<<(MTOT / 256) * (DOUT / 256), 512, 131072, stream>>>(Xcat, Wcat, out);
}

// Round 4
// 327.826 us; speedup vs baseline: 1.0281x; 1.0281x over previous
//
#include <hip/hip_runtime.h>
#include <hip/hip_bf16.h>
#include <stdint.h>

// LoRA int8-dequant linear, MI355X/gfx950.
//   Xb[8192][4096]  = bf16(x)
//   Wb[4096][4096]  = bf16(qweight*scale)
//   xa[8192][64]    = bf16(Xb @ Abf^T)      (LoRA left factor)
//   Blt[4096][64]   = bf16(2*lora_B)
//   out = Xb @ Wb^T + xa @ Blt^T   (fp32 out, fp32 accum; lora = epilogue K-tile)
// Main GEMM: 256x256 tile, BK=64, 8 waves, 4-phase/K-tile, 8/8/4/4 ds_read
// distribution, counted vmcnt(4), T2 LDS swizzle, T5 setprio, XCD swizzle.

typedef __bf16 bf16x8 __attribute__((ext_vector_type(8)));
typedef float f32x4 __attribute__((ext_vector_type(4)));

#define DIN   4096
#define DOUT  4096
#define MTOT  8192
#define RNK   64
#define NT    64            // K-tiles of 64 (main GEMM K = 4096)

__device__ inline void gload_lds16(const void* g, void* l) {
  __builtin_amdgcn_global_load_lds((const __attribute__((address_space(1))) void*)g,
                                   (__attribute__((address_space(3))) void*)l,
                                   16, 0, 0);
}

// ---- x (fp32) -> Xb bf16 ----
__global__ void cvt_x_kernel(const float* __restrict__ x, __bf16* __restrict__ Xb) {
  int i = blockIdx.x * blockDim.x + threadIdx.x;
  int row = i >> 10;
  int c4 = (i & 1023) << 2;
  float4 v = *(const float4*)(x + (size_t)row * DIN + c4);
  union { __bf16 h[4]; uint64_t u; } p;
  p.h[0] = (__bf16)v.x; p.h[1] = (__bf16)v.y;
  p.h[2] = (__bf16)v.z; p.h[3] = (__bf16)v.w;
  *(uint64_t*)(Xb + (size_t)row * DIN + c4) = p.u;
}

// ---- qweight * scale[row] -> Wb bf16 ----
__global__ void cvt_w_kernel(const int* __restrict__ q, const float* __restrict__ scale,
                             __bf16* __restrict__ Wb) {
  int i = blockIdx.x * blockDim.x + threadIdx.x;
  int row = i >> 10;
  int c4 = (i & 1023) << 2;
  int4 v = *(const int4*)(q + (size_t)row * DIN + c4);
  float s = scale[row];
  union { __bf16 h[4]; uint64_t u; } p;
  p.h[0] = (__bf16)((float)v.x * s); p.h[1] = (__bf16)((float)v.y * s);
  p.h[2] = (__bf16)((float)v.z * s); p.h[3] = (__bf16)((float)v.w * s);
  *(uint64_t*)(Wb + (size_t)row * DIN + c4) = p.u;
}

// ---- lora_A -> Abf [64][4096]; 2*lora_B -> Blt [4096][64] ----
__global__ void cvt_ab_kernel(const float* __restrict__ A, const float* __restrict__ B,
                              __bf16* __restrict__ Abf, __bf16* __restrict__ Blt) {
  int i = blockIdx.x * blockDim.x + threadIdx.x;
  {
    int row = i >> 10;
    int c4 = (i & 1023) << 2;
    float4 v = *(const float4*)(A + (size_t)row * DIN + c4);
    union { __bf16 h[4]; uint64_t u; } p;
    p.h[0] = (__bf16)v.x; p.h[1] = (__bf16)v.y;
    p.h[2] = (__bf16)v.z; p.h[3] = (__bf16)v.w;
    *(uint64_t*)(Abf + (size_t)row * DIN + c4) = p.u;
  }
  {
    int row = i >> 4;
    int r4 = (i & 15) << 2;
    float4 v = *(const float4*)(B + (size_t)row * RNK + r4);
    union { __bf16 h[4]; uint64_t u; } p;
    p.h[0] = (__bf16)(2.0f * v.x); p.h[1] = (__bf16)(2.0f * v.y);
    p.h[2] = (__bf16)(2.0f * v.z); p.h[3] = (__bf16)(2.0f * v.w);
    *(uint64_t*)(Blt + (size_t)row * RNK + r4) = p.u;
  }
}

// ---- xa = Xb @ Abf^T -> bf16 [8192][64] ----
__global__ __launch_bounds__(128) void lora_xa_kernel(const __bf16* __restrict__ Xb,
                                                      const __bf16* __restrict__ Abf,
                                                      __bf16* __restrict__ xa) {
  int wid = threadIdx.x >> 6, lane = threadIdx.x & 63;
  int rowbase = blockIdx.x * 32 + wid * 16;
  f32x4 acc[4] = {};
  const __bf16* xrow = Xb + (size_t)(rowbase + (lane & 15)) * DIN + ((lane >> 4) * 8);
  for (int k0 = 0; k0 < DIN; k0 += 32) {
    bf16x8 af = *(const bf16x8*)(xrow + k0);
#pragma unroll
    for (int ni = 0; ni < 4; ++ni) {
      bf16x8 bfv = *(const bf16x8*)(Abf + (size_t)(ni * 16 + (lane & 15)) * DIN + k0 + (lane >> 4) * 8);
      acc[ni] = __builtin_amdgcn_mfma_f32_16x16x32_bf16(af, bfv, acc[ni], 0, 0, 0);
    }
  }
#pragma unroll
  for (int ni = 0; ni < 4; ++ni)
#pragma unroll
    for (int j = 0; j < 4; ++j) {
      int row = rowbase + (lane >> 4) * 4 + j;
      int col = ni * 16 + (lane & 15);
      xa[(size_t)row * RNK + col] = (__bf16)acc[ni][j];
    }
}

// ==== main GEMM: 256x256 tile, 8 waves, 4-phase/K-tile, 8/8/4/4 reads ====
// LDS (128 KiB dynamic): buf[2] x { A0, A1, B0, B1 } x 16 KiB halves.
// Half = 128 rows x 64 cols bf16, row r at bytes r*128 + (c ^ ((r&7)<<4)).
// Tile kt (cur=kt&1):
//   ph0: read alo-ks0(4)+b-ks0(4); stage B1(kt+1)->buf^1; bar; MFMA(ks0,lo); bar
//   ph1: read alo-ks1(4)+b-ks1(4); stage A1(kt+1)->buf^1; bar; MFMA(ks1,lo); bar
//   ph2: read ahi-ks0(4);          stage B0(kt+2)->buf;   bar; MFMA(ks0,hi); bar
//   ph3: read ahi-ks1(4); lgkm(0); bar; stage A0(kt+2)->buf;   MFMA(ks1,hi);
//        vmcnt(4); bar
// vmcnt(4) leaves only kt+2's B0/A0 (2 loads each) in flight => all of kt+1
// landed at tile end. Cross-wave slot safety: every stage is issued after a
// barrier that follows every wave's drain of that slot's last reads.
// Epilogue: LoRA as one more K=64 tile from LDS-staged xa / Blt into same acc.
__global__ __launch_bounds__(512, 1) void gemm8_kernel(const __bf16* __restrict__ Xc,
                                                       const __bf16* __restrict__ Wc,
                                                       const __bf16* __restrict__ xa,
                                                       const __bf16* __restrict__ Blt,
                                                       float* __restrict__ out) {
  extern __shared__ char smem[];
  const int tid = threadIdx.x;
  const int lane = tid & 63;
  const int w = tid >> 6;        // wave 0..7
  const int wr = w >> 2;         // 0..1 -> rows wr*128
  const int wc = w & 3;          // 0..3 -> cols wc*64

  // bijective XCD swizzle (nwg=512, 512%8==0)
  const int swz = (blockIdx.x & 7) * 64 + (blockIdx.x >> 3);
  const int bx = swz & 15;       // N tile 0..15
  const int by = swz >> 4;       // M tile 0..31
  const size_t bm = (size_t)by * 256, bn = (size_t)bx * 256;

  const char* Ab = (const char*)Xc;
  const char* Bb = (const char*)Wc;

  // staging lane constants
  const int sl_row = lane >> 3;
  const int sl_col = 16 * ((lane & 7) ^ (lane >> 3));   // inverse-swizzled source col

  // read-side swizzled col byte offsets for ks=0/1
  const int cx0 = (((lane >> 4) << 4)) ^ ((lane & 7) << 4);
  const int cx1 = (64 | ((lane >> 4) << 4)) ^ ((lane & 7) << 4);

  auto STAGEP = [&](const char* g, size_t pitchB, size_t r0, int ldsoff, size_t colB) {
    char* d0 = smem + ldsoff + (w * 2) * 1024 + lane * 16;
#pragma unroll
    for (int s = 0; s < 2; ++s) {
      const int rl = (w * 2 + s) * 8 + sl_row;
      gload_lds16(g + (r0 + rl) * pitchB + colB + sl_col, d0 + s * 1024);
    }
  };
  auto STAGE = [&](int st, int buf, int isB, int h) {
    STAGEP(isB ? Bb : Ab, 8192, (isB ? bn : bm) + (size_t)h * 128,
           buf * 65536 + isB * 32768 + h * 16384, (size_t)st * 128);
  };

  bf16x8 alo[4], ahi[4], b[4][2];
  f32x4 acc[8][4] = {};

  // ---- prologue: tile0 all 4 halves, then tile1's {B0, A0}; vmcnt(4) -> t0 landed ----
  STAGE(0, 0, 0, 0); STAGE(0, 0, 0, 1); STAGE(0, 0, 1, 0); STAGE(0, 0, 1, 1);
  STAGE(1, 1, 1, 0); STAGE(1, 1, 0, 0);
  asm volatile("s_waitcnt vmcnt(4)" ::: "memory");
  __builtin_amdgcn_s_barrier();

  auto tile = [&](int kt, bool s1, bool s2, int wm) {
    const int cur = kt & 1;
    const int abase = cur * 65536 + wr * 16384 + (lane & 15) * 128;
    const int bbase = cur * 65536 + 32768 + (wc >> 1) * 16384 + ((wc & 1) * 64 + (lane & 15)) * 128;

    // ---------- phase 0: (ks0, mi-lo) ----------
#pragma unroll
    for (int mi = 0; mi < 4; ++mi)
      alo[mi] = *(const bf16x8*)(smem + abase + mi * 2048 + cx0);
#pragma unroll
    for (int ni = 0; ni < 4; ++ni)
      b[ni][0] = *(const bf16x8*)(smem + bbase + ni * 2048 + cx0);
    if (s1) STAGE(kt + 1, cur ^ 1, 1, 1);
    __builtin_amdgcn_s_barrier();
    __builtin_amdgcn_s_setprio(1);
#pragma unroll
    for (int mi = 0; mi < 4; ++mi)
#pragma unroll
      for (int ni = 0; ni < 4; ++ni)
        acc[mi][ni] = __builtin_amdgcn_mfma_f32_16x16x32_bf16(alo[mi], b[ni][0], acc[mi][ni], 0, 0, 0);
    __builtin_amdgcn_s_setprio(0);
    __builtin_amdgcn_s_barrier();

    // ---------- phase 1: (ks1, mi-lo) ----------
#pragma unroll
    for (int mi = 0; mi < 4; ++mi)
      alo[mi] = *(const bf16x8*)(smem + abase + mi * 2048 + cx1);
#pragma unroll
    for (int ni = 0; ni < 4; ++ni)
      b[ni][1] = *(const bf16x8*)(smem + bbase + ni * 2048 + cx1);
    if (s1) STAGE(kt + 1, cur ^ 1, 0, 1);
    __builtin_amdgcn_s_barrier();
    __builtin_amdgcn_s_setprio(1);
#pragma unroll
    for (int mi = 0; mi < 4; ++mi)
#pragma unroll
      for (int ni = 0; ni < 4; ++ni)
        acc[mi][ni] = __builtin_amdgcn_mfma_f32_16x16x32_bf16(alo[mi], b[ni][1], acc[mi][ni], 0, 0, 0);
    __builtin_amdgcn_s_setprio(0);
    __builtin_amdgcn_s_barrier();

    // ---------- phase 2: (ks0, mi-hi) ----------
#pragma unroll
    for (int mi = 0; mi < 4; ++mi)
      ahi[mi] = *(const bf16x8*)(smem + abase + 8192 + mi * 2048 + cx0);
    if (s2) STAGE(kt + 2, cur, 1, 0);
    __builtin_amdgcn_s_barrier();
    __builtin_amdgcn_s_setprio(1);
#pragma unroll
    for (int mi = 0; mi < 4; ++mi)
#pragma unroll
      for (int ni = 0; ni < 4; ++ni)
        acc[4 + mi][ni] = __builtin_amdgcn_mfma_f32_16x16x32_bf16(ahi[mi], b[ni][0], acc[4 + mi][ni], 0, 0, 0);
    __builtin_amdgcn_s_setprio(0);
    __builtin_amdgcn_s_barrier();

    // ---------- phase 3: (ks1, mi-hi) ----------
#pragma unroll
    for (int mi = 0; mi < 4; ++mi)
      ahi[mi] = *(const bf16x8*)(smem + abase + 8192 + mi * 2048 + cx1);
    asm volatile("s_waitcnt lgkmcnt(0)" ::: "memory");   // all waves drain A reads
    __builtin_amdgcn_sched_barrier(0);
    __builtin_amdgcn_s_barrier();                         // ... before A0 overwrite
    if (s2) STAGE(kt + 2, cur, 0, 0);
    __builtin_amdgcn_s_setprio(1);
#pragma unroll
    for (int mi = 0; mi < 4; ++mi)
#pragma unroll
      for (int ni = 0; ni < 4; ++ni)
        acc[4 + mi][ni] = __builtin_amdgcn_mfma_f32_16x16x32_bf16(ahi[mi], b[ni][1], acc[4 + mi][ni], 0, 0, 0);
    __builtin_amdgcn_s_setprio(0);
    __builtin_amdgcn_sched_barrier(0);
    if (wm == 0) { asm volatile("s_waitcnt vmcnt(4)" ::: "memory"); }
    else if (wm == 1) { asm volatile("s_waitcnt vmcnt(0)" ::: "memory"); }
    __builtin_amdgcn_s_barrier();
  };

  for (int kt = 0; kt < NT - 2; ++kt) tile(kt, true, true, 0);
  tile(NT - 2, true, false, 1);   // no kt+2 stages; drain all of tile NT-1
  tile(NT - 1, false, false, 2);  // no stages, no wait

  // ---- LoRA epilogue: one K=64 tile from xa / Blt via buf0 ----
  STAGEP((const char*)xa, 128, bm, 0, 0);
  STAGEP((const char*)xa, 128, bm + 128, 16384, 0);
  STAGEP((const char*)Blt, 128, bn, 32768, 0);
  STAGEP((const char*)Blt, 128, bn + 128, 49152, 0);
  asm volatile("s_waitcnt vmcnt(0)" ::: "memory");
  __builtin_amdgcn_s_barrier();
  {
    const int abase = wr * 16384 + (lane & 15) * 128;
    const int bbase = 32768 + (wc >> 1) * 16384 + ((wc & 1) * 64 + (lane & 15)) * 128;
    bf16x8 bl[4][2];
#pragma unroll
    for (int ni = 0; ni < 4; ++ni) {
      bl[ni][0] = *(const bf16x8*)(smem + bbase + ni * 2048 + cx0);
      bl[ni][1] = *(const bf16x8*)(smem + bbase + ni * 2048 + cx1);
    }
#pragma unroll
    for (int mi = 0; mi < 8; ++mi) {
      bf16x8 ax0 = *(const bf16x8*)(smem + abase + mi * 2048 + cx0);
      bf16x8 ax1 = *(const bf16x8*)(smem + abase + mi * 2048 + cx1);
#pragma unroll
      for (int ni = 0; ni < 4; ++ni) {
        acc[mi][ni] = __builtin_amdgcn_mfma_f32_16x16x32_bf16(ax0, bl[ni][0], acc[mi][ni], 0, 0, 0);
        acc[mi][ni] = __builtin_amdgcn_mfma_f32_16x16x32_bf16(ax1, bl[ni][1], acc[mi][ni], 0, 0, 0);
      }
    }
  }

  // ---- epilogue: C write ----
#pragma unroll
  for (int mi = 0; mi < 8; ++mi)
#pragma unroll
    for (int ni = 0; ni < 4; ++ni) {
      const size_t row = bm + wr * 128 + mi * 16 + (lane >> 4) * 4;
      const size_t col = bn + wc * 64 + ni * 16 + (lane & 15);
#pragma unroll
      for (int j = 0; j < 4; ++j)
        out[(row + j) * DOUT + col] = acc[mi][ni][j];
    }
}

extern "C" void kernel_launch(void* const* d_in, const int* in_sizes, int n_in,
                              void* d_out, int out_size, void* d_ws, size_t ws_size,
                              hipStream_t stream) {
  const float* x = (const float*)d_in[0];
  const int* qw = (const int*)d_in[1];
  const float* scale = (const float*)d_in[2];
  const float* lA = (const float*)d_in[3];
  const float* lB = (const float*)d_in[4];
  float* out = (float*)d_out;

  char* ws = (char*)d_ws;
  __bf16* Xb  = (__bf16*)ws;                                   // 67.1 MB
  __bf16* Wb  = (__bf16*)(ws + (size_t)MTOT * DIN * 2);        // 33.6 MB
  __bf16* xa  = (__bf16*)(ws + (size_t)(MTOT + DOUT) * DIN * 2);       // 1.05 MB
  __bf16* Abf = (__bf16*)(ws + (size_t)(MTOT + DOUT) * DIN * 2 + (size_t)MTOT * RNK * 2);
  __bf16* Blt = (__bf16*)(ws + (size_t)(MTOT + DOUT) * DIN * 2 + (size_t)(MTOT + RNK) * RNK * 2);

  hipFuncSetAttribute((const void*)gemm8_kernel,
                      hipFuncAttributeMaxDynamicSharedMemorySize, 131072);

  cvt_x_kernel<<<MTOT * (DIN / 4) / 256, 256, 0, stream>>>(x, Xb);
  cvt_w_kernel<<<DOUT * (DIN / 4) / 256, 256, 0, stream>>>(qw, scale, Wb);
  cvt_ab_kernel<<<RNK * (DIN / 4) / 256, 256, 0, stream>>>(lA, lB, Abf, Blt);
  lora_xa_kernel<<<MTOT / 32, 128, 0, stream>>>(Xb, Abf, xa);
  gemm8_kernel<<<(MTOT / 256) * (DOUT / 256), 512, 131072, stream>>>(Xb, Wb, xa, Blt, out);
}

// Round 5
// 321.710 us; speedup vs baseline: 1.0476x; 1.0190x over previous
//
#include <hip/hip_runtime.h>
#include <hip/hip_bf16.h>
#include <stdint.h>

// LoRA int8-dequant linear, MI355X/gfx950.
//   Xb[8192][4096]  = bf16(x)
//   Wb[4096][4096]  = bf16(qweight*scale)
//   xa[8192][64]    = bf16(Xb @ Abf^T)      (LoRA left factor)
//   Blt[4096][64]   = bf16(2*lora_B)
//   out = Xb @ Wb^T + xa @ Blt^T   (fp32 out, fp32 accum; lora = epilogue K-tile)
// Main GEMM: 256x256 tile, BK=64, 8 waves, 4-phase/K-tile, ONE barrier per
// phase (reads/MFMA overlap across waves), counted vmcnt(4), T2 swizzle, T5.

typedef __bf16 bf16x8 __attribute__((ext_vector_type(8)));
typedef float f32x4 __attribute__((ext_vector_type(4)));

#define DIN   4096
#define DOUT  4096
#define MTOT  8192
#define RNK   64
#define NT    64            // K-tiles of 64 (main GEMM K = 4096)

__device__ inline void gload_lds16(const void* g, void* l) {
  __builtin_amdgcn_global_load_lds((const __attribute__((address_space(1))) void*)g,
                                   (__attribute__((address_space(3))) void*)l,
                                   16, 0, 0);
}

// ---- x (fp32) -> Xb bf16 ----
__global__ void cvt_x_kernel(const float* __restrict__ x, __bf16* __restrict__ Xb) {
  int i = blockIdx.x * blockDim.x + threadIdx.x;
  int row = i >> 10;
  int c4 = (i & 1023) << 2;
  float4 v = *(const float4*)(x + (size_t)row * DIN + c4);
  union { __bf16 h[4]; uint64_t u; } p;
  p.h[0] = (__bf16)v.x; p.h[1] = (__bf16)v.y;
  p.h[2] = (__bf16)v.z; p.h[3] = (__bf16)v.w;
  *(uint64_t*)(Xb + (size_t)row * DIN + c4) = p.u;
}

// ---- qweight * scale[row] -> Wb bf16 ----
__global__ void cvt_w_kernel(const int* __restrict__ q, const float* __restrict__ scale,
                             __bf16* __restrict__ Wb) {
  int i = blockIdx.x * blockDim.x + threadIdx.x;
  int row = i >> 10;
  int c4 = (i & 1023) << 2;
  int4 v = *(const int4*)(q + (size_t)row * DIN + c4);
  float s = scale[row];
  union { __bf16 h[4]; uint64_t u; } p;
  p.h[0] = (__bf16)((float)v.x * s); p.h[1] = (__bf16)((float)v.y * s);
  p.h[2] = (__bf16)((float)v.z * s); p.h[3] = (__bf16)((float)v.w * s);
  *(uint64_t*)(Wb + (size_t)row * DIN + c4) = p.u;
}

// ---- lora_A -> Abf [64][4096]; 2*lora_B -> Blt [4096][64] ----
__global__ void cvt_ab_kernel(const float* __restrict__ A, const float* __restrict__ B,
                              __bf16* __restrict__ Abf, __bf16* __restrict__ Blt) {
  int i = blockIdx.x * blockDim.x + threadIdx.x;
  {
    int row = i >> 10;
    int c4 = (i & 1023) << 2;
    float4 v = *(const float4*)(A + (size_t)row * DIN + c4);
    union { __bf16 h[4]; uint64_t u; } p;
    p.h[0] = (__bf16)v.x; p.h[1] = (__bf16)v.y;
    p.h[2] = (__bf16)v.z; p.h[3] = (__bf16)v.w;
    *(uint64_t*)(Abf + (size_t)row * DIN + c4) = p.u;
  }
  {
    int row = i >> 4;
    int r4 = (i & 15) << 2;
    float4 v = *(const float4*)(B + (size_t)row * RNK + r4);
    union { __bf16 h[4]; uint64_t u; } p;
    p.h[0] = (__bf16)(2.0f * v.x); p.h[1] = (__bf16)(2.0f * v.y);
    p.h[2] = (__bf16)(2.0f * v.z); p.h[3] = (__bf16)(2.0f * v.w);
    *(uint64_t*)(Blt + (size_t)row * RNK + r4) = p.u;
  }
}

// ---- xa = Xb @ Abf^T -> bf16 [8192][64] ----
__global__ __launch_bounds__(128) void lora_xa_kernel(const __bf16* __restrict__ Xb,
                                                      const __bf16* __restrict__ Abf,
                                                      __bf16* __restrict__ xa) {
  int wid = threadIdx.x >> 6, lane = threadIdx.x & 63;
  int rowbase = blockIdx.x * 32 + wid * 16;
  f32x4 acc[4] = {};
  const __bf16* xrow = Xb + (size_t)(rowbase + (lane & 15)) * DIN + ((lane >> 4) * 8);
  for (int k0 = 0; k0 < DIN; k0 += 32) {
    bf16x8 af = *(const bf16x8*)(xrow + k0);
#pragma unroll
    for (int ni = 0; ni < 4; ++ni) {
      bf16x8 bfv = *(const bf16x8*)(Abf + (size_t)(ni * 16 + (lane & 15)) * DIN + k0 + (lane >> 4) * 8);
      acc[ni] = __builtin_amdgcn_mfma_f32_16x16x32_bf16(af, bfv, acc[ni], 0, 0, 0);
    }
  }
#pragma unroll
  for (int ni = 0; ni < 4; ++ni)
#pragma unroll
    for (int j = 0; j < 4; ++j) {
      int row = rowbase + (lane >> 4) * 4 + j;
      int col = ni * 16 + (lane & 15);
      xa[(size_t)row * RNK + col] = (__bf16)acc[ni][j];
    }
}

// ==== main GEMM: 256x256 tile, 8 waves, 4-phase/K-tile, 1 barrier/phase ====
// LDS (128 KiB dynamic): buf[2] x { A0, A1, B0, B1 } x 16 KiB halves.
// Half = 128 rows x 64 cols bf16, row r at bytes r*128 + (c ^ ((r&7)<<4)).
// Tile kt (cur=kt&1):
//   ph0: read alo-ks0(4)+b-ks0(4); STAGE B1(kt+1)->buf^1; MFMA(ks0,lo); bar
//   ph1: read alo-ks1(4)+b-ks1(4); STAGE A1(kt+1)->buf^1; MFMA(ks1,lo); bar
//   ph2: read ahi-ks0/ks1(8);      STAGE B0(kt+2)->cur;   MFMA(ks0,hi);
//        lgkm(0) [drain ahi-ks1 before ph3's A0 overwrite]; bar
//   ph3: STAGE A0(kt+2)->cur;                             MFMA(ks1,hi);
//        vmcnt(4); bar
// Cross-wave slot safety: every STAGE's target slot had its last ds_read
// consumed by an MFMA (or drained by lgkm(0)) before a barrier separating it
// from the write. vmcnt(4) at tile end lands all of kt+1, leaves kt+2's
// B0/A0 (4 loads) in flight. Single barrier/phase lets one wave's ds_reads
// overlap another wave's MFMA cluster (setprio arbitrates).
__global__ __launch_bounds__(512, 1) void gemm8_kernel(const __bf16* __restrict__ Xc,
                                                       const __bf16* __restrict__ Wc,
                                                       const __bf16* __restrict__ xa,
                                                       const __bf16* __restrict__ Blt,
                                                       float* __restrict__ out) {
  extern __shared__ char smem[];
  const int tid = threadIdx.x;
  const int lane = tid & 63;
  const int w = tid >> 6;        // wave 0..7
  const int wr = w >> 2;         // 0..1 -> rows wr*128
  const int wc = w & 3;          // 0..3 -> cols wc*64

  // bijective XCD swizzle (nwg=512, 512%8==0)
  const int swz = (blockIdx.x & 7) * 64 + (blockIdx.x >> 3);
  const int bx = swz & 15;       // N tile 0..15
  const int by = swz >> 4;       // M tile 0..31
  const size_t bm = (size_t)by * 256, bn = (size_t)bx * 256;

  const char* Ab = (const char*)Xc;
  const char* Bb = (const char*)Wc;

  // staging lane constants
  const int sl_row = lane >> 3;
  const int sl_col = 16 * ((lane & 7) ^ (lane >> 3));   // inverse-swizzled source col

  // read-side swizzled col byte offsets for ks=0/1
  const int cx0 = (((lane >> 4) << 4)) ^ ((lane & 7) << 4);
  const int cx1 = (64 | ((lane >> 4) << 4)) ^ ((lane & 7) << 4);

  auto STAGEP = [&](const char* g, size_t pitchB, size_t r0, int ldsoff, size_t colB) {
    char* d0 = smem + ldsoff + (w * 2) * 1024 + lane * 16;
#pragma unroll
    for (int s = 0; s < 2; ++s) {
      const int rl = (w * 2 + s) * 8 + sl_row;
      gload_lds16(g + (r0 + rl) * pitchB + colB + sl_col, d0 + s * 1024);
    }
  };
  auto STAGE = [&](int st, int buf, int isB, int h) {
    STAGEP(isB ? Bb : Ab, 8192, (isB ? bn : bm) + (size_t)h * 128,
           buf * 65536 + isB * 32768 + h * 16384, (size_t)st * 128);
  };

  bf16x8 alo[4], ahi[4][2], b[4][2];
  f32x4 acc[8][4] = {};

  // ---- prologue: tile0 all 4 halves, then tile1's {B0, A0}; vmcnt(4) -> t0 landed ----
  STAGE(0, 0, 1, 0); STAGE(0, 0, 0, 0); STAGE(0, 0, 1, 1); STAGE(0, 0, 0, 1);
  STAGE(1, 1, 1, 0); STAGE(1, 1, 0, 0);
  asm volatile("s_waitcnt vmcnt(4)" ::: "memory");
  __builtin_amdgcn_s_barrier();

  auto tile = [&](int kt, bool s1, bool s2, int wm) {
    const int cur = kt & 1;
    const int abase = cur * 65536 + wr * 16384 + (lane & 15) * 128;
    const int bbase = cur * 65536 + 32768 + (wc >> 1) * 16384 + ((wc & 1) * 64 + (lane & 15)) * 128;

    // ---------- phase 0: (ks0, mi-lo) ----------
#pragma unroll
    for (int mi = 0; mi < 4; ++mi)
      alo[mi] = *(const bf16x8*)(smem + abase + mi * 2048 + cx0);
#pragma unroll
    for (int ni = 0; ni < 4; ++ni)
      b[ni][0] = *(const bf16x8*)(smem + bbase + ni * 2048 + cx0);
    if (s1) STAGE(kt + 1, cur ^ 1, 1, 1);
    __builtin_amdgcn_s_setprio(1);
#pragma unroll
    for (int mi = 0; mi < 4; ++mi)
#pragma unroll
      for (int ni = 0; ni < 4; ++ni)
        acc[mi][ni] = __builtin_amdgcn_mfma_f32_16x16x32_bf16(alo[mi], b[ni][0], acc[mi][ni], 0, 0, 0);
    __builtin_amdgcn_s_setprio(0);
    __builtin_amdgcn_sched_barrier(0);
    __builtin_amdgcn_s_barrier();

    // ---------- phase 1: (ks1, mi-lo) ----------
#pragma unroll
    for (int mi = 0; mi < 4; ++mi)
      alo[mi] = *(const bf16x8*)(smem + abase + mi * 2048 + cx1);
#pragma unroll
    for (int ni = 0; ni < 4; ++ni)
      b[ni][1] = *(const bf16x8*)(smem + bbase + ni * 2048 + cx1);
    if (s1) STAGE(kt + 1, cur ^ 1, 0, 1);
    __builtin_amdgcn_s_setprio(1);
#pragma unroll
    for (int mi = 0; mi < 4; ++mi)
#pragma unroll
      for (int ni = 0; ni < 4; ++ni)
        acc[mi][ni] = __builtin_amdgcn_mfma_f32_16x16x32_bf16(alo[mi], b[ni][1], acc[mi][ni], 0, 0, 0);
    __builtin_amdgcn_s_setprio(0);
    __builtin_amdgcn_sched_barrier(0);
    __builtin_amdgcn_s_barrier();

    // ---------- phase 2: (ks0, mi-hi) ----------
#pragma unroll
    for (int mi = 0; mi < 4; ++mi) {
      ahi[mi][0] = *(const bf16x8*)(smem + abase + 8192 + mi * 2048 + cx0);
      ahi[mi][1] = *(const bf16x8*)(smem + abase + 8192 + mi * 2048 + cx1);
    }
    if (s2) STAGE(kt + 2, cur, 1, 0);
    __builtin_amdgcn_s_setprio(1);
#pragma unroll
    for (int mi = 0; mi < 4; ++mi)
#pragma unroll
      for (int ni = 0; ni < 4; ++ni)
        acc[4 + mi][ni] = __builtin_amdgcn_mfma_f32_16x16x32_bf16(ahi[mi][0], b[ni][0], acc[4 + mi][ni], 0, 0, 0);
    __builtin_amdgcn_s_setprio(0);
    asm volatile("s_waitcnt lgkmcnt(0)" ::: "memory");   // drain ahi[*][1] before A0 overwrite
    __builtin_amdgcn_sched_barrier(0);
    __builtin_amdgcn_s_barrier();

    // ---------- phase 3: (ks1, mi-hi) ----------
    if (s2) STAGE(kt + 2, cur, 0, 0);
    __builtin_amdgcn_s_setprio(1);
#pragma unroll
    for (int mi = 0; mi < 4; ++mi)
#pragma unroll
      for (int ni = 0; ni < 4; ++ni)
        acc[4 + mi][ni] = __builtin_amdgcn_mfma_f32_16x16x32_bf16(ahi[mi][1], b[ni][1], acc[4 + mi][ni], 0, 0, 0);
    __builtin_amdgcn_s_setprio(0);
    __builtin_amdgcn_sched_barrier(0);
    if (wm == 0) { asm volatile("s_waitcnt vmcnt(4)" ::: "memory"); }
    else if (wm == 1) { asm volatile("s_waitcnt vmcnt(0)" ::: "memory"); }
    __builtin_amdgcn_s_barrier();
  };

  for (int kt = 0; kt < NT - 2; ++kt) tile(kt, true, true, 0);
  tile(NT - 2, true, false, 1);   // no kt+2 stages; drain everything for tile NT-1
  tile(NT - 1, false, false, 2);  // no stages, no wait

  // ---- LoRA epilogue: one K=64 tile from xa / Blt via buf0 ----
  STAGEP((const char*)xa, 128, bm, 0, 0);
  STAGEP((const char*)xa, 128, bm + 128, 16384, 0);
  STAGEP((const char*)Blt, 128, bn, 32768, 0);
  STAGEP((const char*)Blt, 128, bn + 128, 49152, 0);
  asm volatile("s_waitcnt vmcnt(0)" ::: "memory");
  __builtin_amdgcn_s_barrier();
  {
    const int abase = wr * 16384 + (lane & 15) * 128;
    const int bbase = 32768 + (wc >> 1) * 16384 + ((wc & 1) * 64 + (lane & 15)) * 128;
    bf16x8 bl[4][2];
#pragma unroll
    for (int ni = 0; ni < 4; ++ni) {
      bl[ni][0] = *(const bf16x8*)(smem + bbase + ni * 2048 + cx0);
      bl[ni][1] = *(const bf16x8*)(smem + bbase + ni * 2048 + cx1);
    }
#pragma unroll
    for (int mi = 0; mi < 8; ++mi) {
      bf16x8 ax0 = *(const bf16x8*)(smem + abase + mi * 2048 + cx0);
      bf16x8 ax1 = *(const bf16x8*)(smem + abase + mi * 2048 + cx1);
#pragma unroll
      for (int ni = 0; ni < 4; ++ni) {
        acc[mi][ni] = __builtin_amdgcn_mfma_f32_16x16x32_bf16(ax0, bl[ni][0], acc[mi][ni], 0, 0, 0);
        acc[mi][ni] = __builtin_amdgcn_mfma_f32_16x16x32_bf16(ax1, bl[ni][1], acc[mi][ni], 0, 0, 0);
      }
    }
  }

  // ---- epilogue: C write ----
#pragma unroll
  for (int mi = 0; mi < 8; ++mi)
#pragma unroll
    for (int ni = 0; ni < 4; ++ni) {
      const size_t row = bm + wr * 128 + mi * 16 + (lane >> 4) * 4;
      const size_t col = bn + wc * 64 + ni * 16 + (lane & 15);
#pragma unroll
      for (int j = 0; j < 4; ++j)
        out[(row + j) * DOUT + col] = acc[mi][ni][j];
    }
}

extern "C" void kernel_launch(void* const* d_in, const int* in_sizes, int n_in,
                              void* d_out, int out_size, void* d_ws, size_t ws_size,
                              hipStream_t stream) {
  const float* x = (const float*)d_in[0];
  const int* qw = (const int*)d_in[1];
  const float* scale = (const float*)d_in[2];
  const float* lA = (const float*)d_in[3];
  const float* lB = (const float*)d_in[4];
  float* out = (float*)d_out;

  char* ws = (char*)d_ws;
  __bf16* Xb  = (__bf16*)ws;                                   // 67.1 MB
  __bf16* Wb  = (__bf16*)(ws + (size_t)MTOT * DIN * 2);        // 33.6 MB
  __bf16* xa  = (__bf16*)(ws + (size_t)(MTOT + DOUT) * DIN * 2);       // 1.05 MB
  __bf16* Abf = (__bf16*)(ws + (size_t)(MTOT + DOUT) * DIN * 2 + (size_t)MTOT * RNK * 2);
  __bf16* Blt = (__bf16*)(ws + (size_t)(MTOT + DOUT) * DIN * 2 + (size_t)(MTOT + RNK) * RNK * 2);

  hipFuncSetAttribute((const void*)gemm8_kernel,
                      hipFuncAttributeMaxDynamicSharedMemorySize, 131072);

  cvt_x_kernel<<<MTOT * (DIN / 4) / 256, 256, 0, stream>>>(x, Xb);
  cvt_w_kernel<<<DOUT * (DIN / 4) / 256, 256, 0, stream>>>(qw, scale, Wb);
  cvt_ab_kernel<<<RNK * (DIN / 4) / 256, 256, 0, stream>>>(lA, lB, Abf, Blt);
  lora_xa_kernel<<<MTOT / 32, 128, 0, stream>>>(Xb, Abf, xa);
  gemm8_kernel<<<(MTOT / 256) * (DOUT / 256), 512, 131072, stream>>>(Xb, Wb, xa, Blt, out);
}

// Round 6
// 261.388 us; speedup vs baseline: 1.2894x; 1.2308x over previous
//
#include <hip/hip_runtime.h>
#include <hip/hip_bf16.h>
#include <stdint.h>

// LoRA int8-dequant linear, MI355X/gfx950 — int8 main-path GEMM.
//   Xi8[8192][4096] = rne(x * 127/absmax_row),  tstep[m] = absmax_row/127
//   Wi8[4096][4096] = qweight codes (exact i8)
//   out = (Xi8 @ Wi8^T)_i32 * (tstep[m]*scale[o]) + xa @ (2B)^T
// Main GEMM: 256x256 tile, BK=64, 8 waves, mfma_i32_16x16x64_i8, 3-deep LDS
// (96 KB), 2 MFMA clusters + 1 barrier + 1 counted vmcnt(4) per K-tile.
// LoRA epilogue: bf16 MFMA per-frag into transient f32x4, fused with scaling.

typedef __bf16 bf16x8 __attribute__((ext_vector_type(8)));
typedef float f32x4 __attribute__((ext_vector_type(4)));
typedef int i32x4 __attribute__((ext_vector_type(4)));

#define DIN   4096
#define DOUT  4096
#define MTOT  8192
#define RNK   64
#define NT    64

__device__ inline void gload_lds16(const void* g, void* l) {
  __builtin_amdgcn_global_load_lds((const __attribute__((address_space(1))) void*)g,
                                   (__attribute__((address_space(3))) void*)l,
                                   16, 0, 0);
}

// ---- per-row absmax quantize x -> i8 (RNE), record step ----
__global__ __launch_bounds__(256) void quant_x_kernel(const float* __restrict__ x,
                                                      signed char* __restrict__ Xi8,
                                                      float* __restrict__ tstep) {
  const int row = blockIdx.x, t = threadIdx.x;
  const float4* xr = (const float4*)(x + (size_t)row * DIN);
  float4 v[4];
  float m = 0.f;
#pragma unroll
  for (int s = 0; s < 4; ++s) {
    v[s] = xr[t + s * 256];
    m = fmaxf(m, fmaxf(fmaxf(fabsf(v[s].x), fabsf(v[s].y)),
                       fmaxf(fabsf(v[s].z), fabsf(v[s].w))));
  }
#pragma unroll
  for (int off = 32; off > 0; off >>= 1) m = fmaxf(m, __shfl_xor(m, off));
  __shared__ float wm[4];
  if ((t & 63) == 0) wm[t >> 6] = m;
  __syncthreads();
  m = fmaxf(fmaxf(wm[0], wm[1]), fmaxf(wm[2], wm[3]));
  m = fmaxf(m, 1e-30f);
  const float rs = 127.0f / m;
  int* orow = (int*)(Xi8 + (size_t)row * DIN);
#pragma unroll
  for (int s = 0; s < 4; ++s) {
    float e[4] = {v[s].x, v[s].y, v[s].z, v[s].w};
    union { signed char c[4]; int i; } p;
#pragma unroll
    for (int j = 0; j < 4; ++j) {
      int q = __float2int_rn(e[j] * rs);
      q = q > 127 ? 127 : (q < -127 ? -127 : q);
      p.c[j] = (signed char)q;
    }
    orow[t + s * 256] = p.i;
  }
  if (t == 0) tstep[row] = m * (1.0f / 127.0f);
}

// ---- qweight int32 codes -> i8 ----
__global__ void cvt_w_kernel(const int* __restrict__ q, signed char* __restrict__ Wi8) {
  int i = blockIdx.x * blockDim.x + threadIdx.x;   // DOUT*DIN/4 threads
  int4 v = ((const int4*)q)[i];
  union { signed char c[4]; int i; } p;
  p.c[0] = (signed char)v.x; p.c[1] = (signed char)v.y;
  p.c[2] = (signed char)v.z; p.c[3] = (signed char)v.w;
  ((int*)Wi8)[i] = p.i;
}

// ---- lora_A -> Abf [64][4096] bf16; 2*lora_B -> Blt [4096][64] bf16 ----
__global__ void cvt_ab_kernel(const float* __restrict__ A, const float* __restrict__ B,
                              __bf16* __restrict__ Abf, __bf16* __restrict__ Blt) {
  int i = blockIdx.x * blockDim.x + threadIdx.x;
  {
    int row = i >> 10;
    int c4 = (i & 1023) << 2;
    float4 v = *(const float4*)(A + (size_t)row * DIN + c4);
    union { __bf16 h[4]; uint64_t u; } p;
    p.h[0] = (__bf16)v.x; p.h[1] = (__bf16)v.y;
    p.h[2] = (__bf16)v.z; p.h[3] = (__bf16)v.w;
    *(uint64_t*)(Abf + (size_t)row * DIN + c4) = p.u;
  }
  {
    int row = i >> 4;
    int r4 = (i & 15) << 2;
    float4 v = *(const float4*)(B + (size_t)row * RNK + r4);
    union { __bf16 h[4]; uint64_t u; } p;
    p.h[0] = (__bf16)(2.0f * v.x); p.h[1] = (__bf16)(2.0f * v.y);
    p.h[2] = (__bf16)(2.0f * v.z); p.h[3] = (__bf16)(2.0f * v.w);
    *(uint64_t*)(Blt + (size_t)row * RNK + r4) = p.u;
  }
}

// ---- xa = bf16(x) @ Abf^T -> bf16 [8192][64] (reads fp32 x directly) ----
__global__ __launch_bounds__(128) void lora_xa_kernel(const float* __restrict__ x,
                                                      const __bf16* __restrict__ Abf,
                                                      __bf16* __restrict__ xa) {
  int wid = threadIdx.x >> 6, lane = threadIdx.x & 63;
  int rowbase = blockIdx.x * 32 + wid * 16;
  f32x4 acc[4] = {};
  const float* xrow = x + (size_t)(rowbase + (lane & 15)) * DIN + ((lane >> 4) * 8);
  for (int k0 = 0; k0 < DIN; k0 += 32) {
    float4 v0 = *(const float4*)(xrow + k0);
    float4 v1 = *(const float4*)(xrow + k0 + 4);
    bf16x8 af = {(__bf16)v0.x, (__bf16)v0.y, (__bf16)v0.z, (__bf16)v0.w,
                 (__bf16)v1.x, (__bf16)v1.y, (__bf16)v1.z, (__bf16)v1.w};
#pragma unroll
    for (int ni = 0; ni < 4; ++ni) {
      bf16x8 bfv = *(const bf16x8*)(Abf + (size_t)(ni * 16 + (lane & 15)) * DIN + k0 + (lane >> 4) * 8);
      acc[ni] = __builtin_amdgcn_mfma_f32_16x16x32_bf16(af, bfv, acc[ni], 0, 0, 0);
    }
  }
#pragma unroll
  for (int ni = 0; ni < 4; ++ni)
#pragma unroll
    for (int j = 0; j < 4; ++j) {
      int row = rowbase + (lane >> 4) * 4 + j;
      int col = ni * 16 + (lane & 15);
      xa[(size_t)row * RNK + col] = (__bf16)acc[ni][j];
    }
}

// ==== i8 main GEMM ====
// LDS 96 KB: 3 bufs x 32 KB, buf = { A0(8K:rows0-127), A1(8K), B0(8K), B1(8K) }.
// Half = 128 rows x 64 i8; row r, 16B-slot s stored at slot s ^ ((r>>1)&3)
// (conflict-free frag reads; staged via inverse-swizzled global source).
// Tile kt (buf kt%3): reads a-lo(4)+b(4), stageA(kt+2)->buf[(kt+2)%3],
// MFMA 16; reads a-hi(4), stageB(kt+2), MFMA 16; sched_barrier; vmcnt(4); bar.
// vmcnt(4) at tile end forces tile kt+1's 4 halves landed, leaves kt+2's 4
// in flight. Nothing writes the current buf during a tile (3-buf rotation);
// cross-tile WAR protected by the trailing barrier + sched_barrier(0) pin.
__global__ __launch_bounds__(512, 1) void gemm_i8_kernel(const signed char* __restrict__ Xi8,
                                                         const signed char* __restrict__ Wi8,
                                                         const float* __restrict__ scale,
                                                         const float* __restrict__ tstep,
                                                         const __bf16* __restrict__ xa,
                                                         const __bf16* __restrict__ Blt,
                                                         float* __restrict__ out) {
  extern __shared__ char smem[];
  const int tid = threadIdx.x;
  const int lane = tid & 63;
  const int w = tid >> 6;
  const int wr = w >> 2;         // 0..1 -> rows wr*128
  const int wc = w & 3;          // 0..3 -> cols wc*64

  const int swz = (blockIdx.x & 7) * 64 + (blockIdx.x >> 3);  // bijective XCD swizzle
  const int bx = swz & 15;
  const int by = swz >> 4;
  const size_t bm = (size_t)by * 256, bn = (size_t)bx * 256;

  // i8 read swizzle: frag row (l&15)+base, logical 16B-slot (l>>4)
  const int rc = ((lane >> 4) ^ ((lane >> 1) & 3)) << 4;
  // i8 stage constants: thread t -> LDS byte t*16 (row t>>2, phys slot t&3)
  const int srow = tid >> 2;
  const int scol = ((tid & 3) ^ ((tid >> 3) & 3)) << 4;

  auto SH = [&](const signed char* g, size_t r0, int kt, int ldsoff) {
    gload_lds16(g + (r0 + srow) * (size_t)4096 + kt * 64 + scol,
                smem + ldsoff + tid * 16);
  };
  auto stageA = [&](int kt) {
    int b = (kt % 3) * 32768;
    SH(Xi8, bm, kt, b); SH(Xi8, bm + 128, kt, b + 8192);
  };
  auto stageB = [&](int kt) {
    int b = (kt % 3) * 32768;
    SH(Wi8, bn, kt, b + 16384); SH(Wi8, bn + 128, kt, b + 24576);
  };

  i32x4 a[4], a2[4], b[4];
  i32x4 acc[8][4] = {};

  // prologue: tiles 0,1 fully staged; vmcnt(4) -> tile0 landed
  stageA(0); stageB(0); stageA(1); stageB(1);
  asm volatile("s_waitcnt vmcnt(4)" ::: "memory");
  __builtin_amdgcn_s_barrier();

  auto tile = [&](int kt, bool st, int wm) {
    const int bufb = (kt % 3) * 32768;
    const int ab = bufb + wr * 8192 + (lane & 15) * 64 + rc;
    const int bb = bufb + 16384 + (wc >> 1) * 8192 + (wc & 1) * 4096 + (lane & 15) * 64 + rc;
#pragma unroll
    for (int mi = 0; mi < 4; ++mi)
      a[mi] = *(const i32x4*)(smem + ab + mi * 1024);
#pragma unroll
    for (int ni = 0; ni < 4; ++ni)
      b[ni] = *(const i32x4*)(smem + bb + ni * 1024);
    if (st) stageA(kt + 2);
    __builtin_amdgcn_s_setprio(1);
#pragma unroll
    for (int mi = 0; mi < 4; ++mi)
#pragma unroll
      for (int ni = 0; ni < 4; ++ni)
        acc[mi][ni] = __builtin_amdgcn_mfma_i32_16x16x64_i8(a[mi], b[ni], acc[mi][ni], 0, 0, 0);
    __builtin_amdgcn_s_setprio(0);
#pragma unroll
    for (int mi = 0; mi < 4; ++mi)
      a2[mi] = *(const i32x4*)(smem + ab + 4096 + mi * 1024);   // rows 64..127
    if (st) stageB(kt + 2);
    __builtin_amdgcn_s_setprio(1);
#pragma unroll
    for (int mi = 0; mi < 4; ++mi)
#pragma unroll
      for (int ni = 0; ni < 4; ++ni)
        acc[4 + mi][ni] = __builtin_amdgcn_mfma_i32_16x16x64_i8(a2[mi], b[ni], acc[4 + mi][ni], 0, 0, 0);
    __builtin_amdgcn_s_setprio(0);
    __builtin_amdgcn_sched_barrier(0);
    if (wm == 0) { asm volatile("s_waitcnt vmcnt(4)" ::: "memory"); }
    else if (wm == 1) { asm volatile("s_waitcnt vmcnt(0)" ::: "memory"); }
    __builtin_amdgcn_s_barrier();
  };

  for (int kt = 0; kt < NT - 2; ++kt) tile(kt, true, 0);
  tile(NT - 2, false, 1);
  tile(NT - 1, false, 2);

  // ---- epilogue: stage xa/Blt (bf16, 64 KB over bufs 0-1) + scales ----
  const int sl_row = lane >> 3;
  const int sl_col = ((lane & 7) ^ (lane >> 3)) << 4;   // bf16 inverse-swizzled src
  auto SBF = [&](const __bf16* g, size_t r0, int ldsoff) {
    char* d0 = smem + ldsoff + w * 2048 + lane * 16;
#pragma unroll
    for (int s = 0; s < 2; ++s) {
      const int rl = (w * 2 + s) * 8 + sl_row;
      gload_lds16((const char*)g + (r0 + rl) * 128 + sl_col, d0 + s * 1024);
    }
  };
  SBF(xa, bm, 0); SBF(xa, bm + 128, 16384);
  SBF(Blt, bn, 32768); SBF(Blt, bn + 128, 49152);

  float sc[4];
#pragma unroll
  for (int ni = 0; ni < 4; ++ni)
    sc[ni] = scale[bn + wc * 64 + ni * 16 + (lane & 15)];
  f32x4 tm[8];
#pragma unroll
  for (int mi = 0; mi < 8; ++mi)
    tm[mi] = *(const f32x4*)&tstep[bm + wr * 128 + mi * 16 + (lane >> 4) * 4];

  asm volatile("s_waitcnt vmcnt(0)" ::: "memory");
  __builtin_amdgcn_s_barrier();

  const int cx0 = ((lane >> 4) << 4) ^ ((lane & 7) << 4);
  const int cx1 = (64 | ((lane >> 4) << 4)) ^ ((lane & 7) << 4);
  const int abE = wr * 16384 + (lane & 15) * 128;
  const int bbE = 32768 + (wc >> 1) * 16384 + ((wc & 1) * 64 + (lane & 15)) * 128;

  bf16x8 bl0[4], bl1[4];
#pragma unroll
  for (int ni = 0; ni < 4; ++ni) {
    bl0[ni] = *(const bf16x8*)(smem + bbE + ni * 2048 + cx0);
    bl1[ni] = *(const bf16x8*)(smem + bbE + ni * 2048 + cx1);
  }
#pragma unroll
  for (int mi = 0; mi < 8; ++mi) {
    bf16x8 ax0 = *(const bf16x8*)(smem + abE + mi * 2048 + cx0);
    bf16x8 ax1 = *(const bf16x8*)(smem + abE + mi * 2048 + cx1);
    const size_t row = bm + wr * 128 + mi * 16 + (lane >> 4) * 4;
#pragma unroll
    for (int ni = 0; ni < 4; ++ni) {
      f32x4 l = {0.f, 0.f, 0.f, 0.f};
      l = __builtin_amdgcn_mfma_f32_16x16x32_bf16(ax0, bl0[ni], l, 0, 0, 0);
      l = __builtin_amdgcn_mfma_f32_16x16x32_bf16(ax1, bl1[ni], l, 0, 0, 0);
      const size_t col = bn + wc * 64 + ni * 16 + (lane & 15);
#pragma unroll
      for (int j = 0; j < 4; ++j)
        out[(row + j) * DOUT + col] = (float)acc[mi][ni][j] * (sc[ni] * tm[mi][j]) + l[j];
    }
  }
}

extern "C" void kernel_launch(void* const* d_in, const int* in_sizes, int n_in,
                              void* d_out, int out_size, void* d_ws, size_t ws_size,
                              hipStream_t stream) {
  const float* x = (const float*)d_in[0];
  const int* qw = (const int*)d_in[1];
  const float* scale = (const float*)d_in[2];
  const float* lA = (const float*)d_in[3];
  const float* lB = (const float*)d_in[4];
  float* out = (float*)d_out;

  char* ws = (char*)d_ws;
  signed char* Xi8 = (signed char*)ws;                              // 33.6 MB
  signed char* Wi8 = (signed char*)(ws + 33554432);                 // 16.8 MB
  __bf16* xa   = (__bf16*)(ws + 50331648);                          // 1.05 MB
  __bf16* Abf  = (__bf16*)(ws + 51380224);                          // 0.52 MB
  __bf16* Blt  = (__bf16*)(ws + 51904512);                          // 0.52 MB
  float*  tstep = (float*)(ws + 52428800);                          // 32 KB

  hipFuncSetAttribute((const void*)gemm_i8_kernel,
                      hipFuncAttributeMaxDynamicSharedMemorySize, 98304);

  quant_x_kernel<<<MTOT, 256, 0, stream>>>(x, Xi8, tstep);
  cvt_w_kernel<<<DOUT * (DIN / 4) / 256, 256, 0, stream>>>(qw, Wi8);
  cvt_ab_kernel<<<RNK * (DIN / 4) / 256, 256, 0, stream>>>(lA, lB, Abf, Blt);
  lora_xa_kernel<<<MTOT / 32, 128, 0, stream>>>(x, Abf, xa);
  gemm_i8_kernel<<<(MTOT / 256) * (DOUT / 256), 512, 98304, stream>>>(
      Xi8, Wi8, scale, tstep, xa, Blt, out);
}

// Round 7
// 212.222 us; speedup vs baseline: 1.5881x; 1.2317x over previous
//
#include <hip/hip_runtime.h>
#include <hip/hip_bf16.h>
#include <stdint.h>

// LoRA int8-dequant linear, MI355X/gfx950 — int8 main path, pipelined ds_reads.
//   Xi8[8192][4096] = rne(x * 127/absmax_row),  tstep[m] = absmax_row/127
//   Wi8[4096][4096] = qweight codes (exact i8)
//   out = (Xi8 @ Wi8^T)_i32 * (tstep[m]*scale[o]) + xa @ (2B)^T
// Main GEMM: 256x256 tile, BK=64, 8 waves, mfma_i32_16x16x64_i8, 4-deep LDS
// (128 KB), ds_reads pipelined one tile ahead so MFMA-lo fires at barrier
// exit; 1 barrier + 1 counted vmcnt(4) per K-tile.

typedef __bf16 bf16x8 __attribute__((ext_vector_type(8)));
typedef float f32x4 __attribute__((ext_vector_type(4)));
typedef int i32x4 __attribute__((ext_vector_type(4)));

#define DIN   4096
#define DOUT  4096
#define MTOT  8192
#define RNK   64
#define NT    64

__device__ inline void gload_lds16(const void* g, void* l) {
  __builtin_amdgcn_global_load_lds((const __attribute__((address_space(1))) void*)g,
                                   (__attribute__((address_space(3))) void*)l,
                                   16, 0, 0);
}

// ---- per-row absmax quantize x -> i8 (RNE), record step ----
__global__ __launch_bounds__(256) void quant_x_kernel(const float* __restrict__ x,
                                                      signed char* __restrict__ Xi8,
                                                      float* __restrict__ tstep) {
  const int row = blockIdx.x, t = threadIdx.x;
  const float4* xr = (const float4*)(x + (size_t)row * DIN);
  float4 v[4];
  float m = 0.f;
#pragma unroll
  for (int s = 0; s < 4; ++s) {
    v[s] = xr[t + s * 256];
    m = fmaxf(m, fmaxf(fmaxf(fabsf(v[s].x), fabsf(v[s].y)),
                       fmaxf(fabsf(v[s].z), fabsf(v[s].w))));
  }
#pragma unroll
  for (int off = 32; off > 0; off >>= 1) m = fmaxf(m, __shfl_xor(m, off));
  __shared__ float wm[4];
  if ((t & 63) == 0) wm[t >> 6] = m;
  __syncthreads();
  m = fmaxf(fmaxf(wm[0], wm[1]), fmaxf(wm[2], wm[3]));
  m = fmaxf(m, 1e-30f);
  const float rs = 127.0f / m;
  int* orow = (int*)(Xi8 + (size_t)row * DIN);
#pragma unroll
  for (int s = 0; s < 4; ++s) {
    float e[4] = {v[s].x, v[s].y, v[s].z, v[s].w};
    union { signed char c[4]; int i; } p;
#pragma unroll
    for (int j = 0; j < 4; ++j) {
      int q = __float2int_rn(e[j] * rs);
      q = q > 127 ? 127 : (q < -127 ? -127 : q);
      p.c[j] = (signed char)q;
    }
    orow[t + s * 256] = p.i;
  }
  if (t == 0) tstep[row] = m * (1.0f / 127.0f);
}

// ---- qweight int32 codes -> i8 ----
__global__ void cvt_w_kernel(const int* __restrict__ q, signed char* __restrict__ Wi8) {
  int i = blockIdx.x * blockDim.x + threadIdx.x;
  int4 v = ((const int4*)q)[i];
  union { signed char c[4]; int i; } p;
  p.c[0] = (signed char)v.x; p.c[1] = (signed char)v.y;
  p.c[2] = (signed char)v.z; p.c[3] = (signed char)v.w;
  ((int*)Wi8)[i] = p.i;
}

// ---- blocks 0..63: quantize lora_A rows -> Ai8/astep; 64..319: 2*lora_B -> Blt bf16 ----
__global__ __launch_bounds__(256) void cvt_ab_kernel(const float* __restrict__ A,
                                                     const float* __restrict__ B,
                                                     signed char* __restrict__ Ai8,
                                                     float* __restrict__ astep,
                                                     __bf16* __restrict__ Blt) {
  const int t = threadIdx.x;
  if (blockIdx.x < 64) {
    const int row = blockIdx.x;
    const float4* ar = (const float4*)(A + (size_t)row * DIN);
    float4 v[4];
    float m = 0.f;
#pragma unroll
    for (int s = 0; s < 4; ++s) {
      v[s] = ar[t + s * 256];
      m = fmaxf(m, fmaxf(fmaxf(fabsf(v[s].x), fabsf(v[s].y)),
                         fmaxf(fabsf(v[s].z), fabsf(v[s].w))));
    }
#pragma unroll
    for (int off = 32; off > 0; off >>= 1) m = fmaxf(m, __shfl_xor(m, off));
    __shared__ float wm[4];
    if ((t & 63) == 0) wm[t >> 6] = m;
    __syncthreads();
    m = fmaxf(fmaxf(wm[0], wm[1]), fmaxf(wm[2], wm[3]));
    m = fmaxf(m, 1e-30f);
    const float rs = 127.0f / m;
    int* orow = (int*)(Ai8 + (size_t)row * DIN);
#pragma unroll
    for (int s = 0; s < 4; ++s) {
      float e[4] = {v[s].x, v[s].y, v[s].z, v[s].w};
      union { signed char c[4]; int i; } p;
#pragma unroll
      for (int j = 0; j < 4; ++j) {
        int q = __float2int_rn(e[j] * rs);
        q = q > 127 ? 127 : (q < -127 ? -127 : q);
        p.c[j] = (signed char)q;
      }
      orow[t + s * 256] = p.i;
    }
    if (t == 0) astep[row] = m * (1.0f / 127.0f);
  } else {
    int i = (blockIdx.x - 64) * 256 + t;    // 65536 threads, 4 els each
    float4 v = ((const float4*)B)[i];
    union { __bf16 h[4]; uint64_t u; } p;
    p.h[0] = (__bf16)(2.0f * v.x); p.h[1] = (__bf16)(2.0f * v.y);
    p.h[2] = (__bf16)(2.0f * v.z); p.h[3] = (__bf16)(2.0f * v.w);
    ((uint64_t*)Blt)[i] = p.u;
  }
}

// ---- xa = (Xi8 @ Ai8^T)*tstep*astep -> bf16 [8192][64] ----
__global__ __launch_bounds__(128) void lora_xa_kernel(const signed char* __restrict__ Xi8,
                                                      const float* __restrict__ tstep,
                                                      const signed char* __restrict__ Ai8,
                                                      const float* __restrict__ astep,
                                                      __bf16* __restrict__ xa) {
  int wid = threadIdx.x >> 6, lane = threadIdx.x & 63;
  int rowbase = blockIdx.x * 32 + wid * 16;
  i32x4 acc[4] = {};
  const signed char* xrow = Xi8 + (size_t)(rowbase + (lane & 15)) * DIN + (lane >> 4) * 16;
  const signed char* ab = Ai8 + (size_t)(lane & 15) * DIN + (lane >> 4) * 16;
  for (int k0 = 0; k0 < DIN; k0 += 64) {
    i32x4 af = *(const i32x4*)(xrow + k0);
#pragma unroll
    for (int ni = 0; ni < 4; ++ni) {
      i32x4 bv = *(const i32x4*)(ab + (size_t)ni * 16 * DIN + k0);
      acc[ni] = __builtin_amdgcn_mfma_i32_16x16x64_i8(af, bv, acc[ni], 0, 0, 0);
    }
  }
  f32x4 tm = *(const f32x4*)&tstep[rowbase + (lane >> 4) * 4];
#pragma unroll
  for (int ni = 0; ni < 4; ++ni) {
    const int col = ni * 16 + (lane & 15);
    const float as = astep[col];
#pragma unroll
    for (int j = 0; j < 4; ++j) {
      int row = rowbase + (lane >> 4) * 4 + j;
      xa[(size_t)row * RNK + col] = (__bf16)((float)acc[ni][j] * tm[j] * as);
    }
  }
}

// ==== i8 main GEMM, pipelined ====
// LDS 128 KB: 4 bufs x 32 KB, buf = { A0(8K rows0-127), A1(8K), B0, B1 }.
// Half = 128 rows x 64 i8; row r, 16B-slot s at phys slot s ^ ((r>>1)&3).
// Body(kt): stage(kt+3)->buf[(kt+3)&3]; ds a2(kt); MFMA lo (operands already
// in regs from previous body); ds a/b of buf[(kt+1)&3] -> next-state regs;
// MFMA hi; vmcnt(4); barrier.  Invariant: at tile-kt start, tiles kt,kt+1
// are landed + barrier-published; stage target buf[(kt-1)&3] had its last
// reads (a2 in body kt-1) drained before that body's end barrier.
__global__ __launch_bounds__(512, 1) void gemm_i8_kernel(const signed char* __restrict__ Xi8,
                                                         const signed char* __restrict__ Wi8,
                                                         const float* __restrict__ scale,
                                                         const float* __restrict__ tstep,
                                                         const __bf16* __restrict__ xa,
                                                         const __bf16* __restrict__ Blt,
                                                         float* __restrict__ out) {
  extern __shared__ char smem[];
  const int tid = threadIdx.x;
  const int lane = tid & 63;
  const int w = tid >> 6;
  const int wr = w >> 2;         // 0..1 -> rows wr*128
  const int wc = w & 3;          // 0..3 -> cols wc*64

  const int swz = (blockIdx.x & 7) * 64 + (blockIdx.x >> 3);  // bijective XCD swizzle
  const int bx = swz & 15;
  const int by = swz >> 4;
  const size_t bm = (size_t)by * 256, bn = (size_t)bx * 256;

  // read swizzle: frag row (l&15)+base, logical 16B-slot (l>>4)
  const int rc = ((lane >> 4) ^ ((lane >> 1) & 3)) << 4;
  // stage constants: thread t -> LDS byte t*16 (row t>>2, phys slot t&3)
  const int srow = tid >> 2;
  const int scol = ((tid & 3) ^ ((tid >> 3) & 3)) << 4;

  auto SH = [&](const signed char* g, size_t r0, int srct, int ldsoff) {
    gload_lds16(g + (r0 + srow) * (size_t)4096 + srct * 64 + scol,
                smem + ldsoff + tid * 16);
  };
  auto stage = [&](int srct, int buf) {
    int b = buf * 32768;
    SH(Xi8, bm, srct, b); SH(Xi8, bm + 128, srct, b + 8192);
    SH(Wi8, bn, srct, b + 16384); SH(Wi8, bn + 128, srct, b + 24576);
  };

  i32x4 aP[4], bP[4], aQ[4], bQ[4], a2[4];
  i32x4 acc[8][4] = {};

  // prologue: tiles 0,1,2 staged; vmcnt(4) -> 0,1 landed; preload tile0 lo+B
  stage(0, 0); stage(1, 1); stage(2, 2);
  asm volatile("s_waitcnt vmcnt(4)" ::: "memory");
  __builtin_amdgcn_s_barrier();
  {
    const int ab0 = wr * 8192 + (lane & 15) * 64 + rc;
    const int bb0 = 16384 + (wc >> 1) * 8192 + (wc & 1) * 4096 + (lane & 15) * 64 + rc;
#pragma unroll
    for (int mi = 0; mi < 4; ++mi) aP[mi] = *(const i32x4*)(smem + ab0 + mi * 1024);
#pragma unroll
    for (int ni = 0; ni < 4; ++ni) bP[ni] = *(const i32x4*)(smem + bb0 + ni * 1024);
  }

  auto body = [&](int kt, auto& ac, auto& bc, auto& an, auto& bn) {
    const int bufb = (kt & 3) * 32768;
    const int ab = bufb + wr * 8192 + (lane & 15) * 64 + rc;
    const int bb = bufb + 16384 + (wc >> 1) * 8192 + (wc & 1) * 4096 + (lane & 15) * 64 + rc;
    const int st = (kt + 3 < NT) ? kt + 3 : NT - 1;   // clamped dummy keeps vmcnt uniform
    stage(st, (kt + 3) & 3);
    // current tile's hi-row A frags
#pragma unroll
    for (int mi = 0; mi < 4; ++mi)
      a2[mi] = *(const i32x4*)(smem + ab + 4096 + mi * 1024);
    __builtin_amdgcn_s_setprio(1);
#pragma unroll
    for (int mi = 0; mi < 4; ++mi)
#pragma unroll
      for (int ni = 0; ni < 4; ++ni)
        acc[mi][ni] = __builtin_amdgcn_mfma_i32_16x16x64_i8(ac[mi], bc[ni], acc[mi][ni], 0, 0, 0);
    __builtin_amdgcn_s_setprio(0);
    // next tile's lo-A + B frags (buffer kt+1 is landed + published)
    const int nbufb = ((kt + 1) & 3) * 32768;
    const int nab = nbufb + wr * 8192 + (lane & 15) * 64 + rc;
    const int nbb = nbufb + 16384 + (wc >> 1) * 8192 + (wc & 1) * 4096 + (lane & 15) * 64 + rc;
#pragma unroll
    for (int mi = 0; mi < 4; ++mi) an[mi] = *(const i32x4*)(smem + nab + mi * 1024);
#pragma unroll
    for (int ni = 0; ni < 4; ++ni) bn[ni] = *(const i32x4*)(smem + nbb + ni * 1024);
    __builtin_amdgcn_s_setprio(1);
#pragma unroll
    for (int mi = 0; mi < 4; ++mi)
#pragma unroll
      for (int ni = 0; ni < 4; ++ni)
        acc[4 + mi][ni] = __builtin_amdgcn_mfma_i32_16x16x64_i8(a2[mi], bc[ni], acc[4 + mi][ni], 0, 0, 0);
    __builtin_amdgcn_s_setprio(0);
    __builtin_amdgcn_sched_barrier(0);
    asm volatile("s_waitcnt vmcnt(4)" ::: "memory");
    __builtin_amdgcn_s_barrier();
  };

  for (int kt = 0; kt < NT; kt += 2) {
    body(kt, aP, bP, aQ, bQ);
    body(kt + 1, aQ, bQ, aP, bP);
  }

  // ---- epilogue: stage xa/Blt (bf16, 64 KB over bufs 0-1) + scales ----
  const int sl_row = lane >> 3;
  const int sl_col = ((lane & 7) ^ (lane >> 3)) << 4;   // bf16 inverse-swizzled src
  auto SBF = [&](const __bf16* g, size_t r0, int ldsoff) {
    char* d0 = smem + ldsoff + w * 2048 + lane * 16;
#pragma unroll
    for (int s = 0; s < 2; ++s) {
      const int rl = (w * 2 + s) * 8 + sl_row;
      gload_lds16((const char*)g + (r0 + rl) * 128 + sl_col, d0 + s * 1024);
    }
  };
  SBF(xa, bm, 0); SBF(xa, bm + 128, 16384);
  SBF(Blt, bn, 32768); SBF(Blt, bn + 128, 49152);

  float sc[4];
#pragma unroll
  for (int ni = 0; ni < 4; ++ni)
    sc[ni] = scale[bn + wc * 64 + ni * 16 + (lane & 15)];
  f32x4 tm[8];
#pragma unroll
  for (int mi = 0; mi < 8; ++mi)
    tm[mi] = *(const f32x4*)&tstep[bm + wr * 128 + mi * 16 + (lane >> 4) * 4];

  asm volatile("s_waitcnt vmcnt(0)" ::: "memory");
  __builtin_amdgcn_s_barrier();

  const int cx0 = ((lane >> 4) << 4) ^ ((lane & 7) << 4);
  const int cx1 = (64 | ((lane >> 4) << 4)) ^ ((lane & 7) << 4);
  const int abE = wr * 16384 + (lane & 15) * 128;
  const int bbE = 32768 + (wc >> 1) * 16384 + ((wc & 1) * 64 + (lane & 15)) * 128;

  bf16x8 bl0[4], bl1[4];
#pragma unroll
  for (int ni = 0; ni < 4; ++ni) {
    bl0[ni] = *(const bf16x8*)(smem + bbE + ni * 2048 + cx0);
    bl1[ni] = *(const bf16x8*)(smem + bbE + ni * 2048 + cx1);
  }
#pragma unroll
  for (int mi = 0; mi < 8; ++mi) {
    bf16x8 ax0 = *(const bf16x8*)(smem + abE + mi * 2048 + cx0);
    bf16x8 ax1 = *(const bf16x8*)(smem + abE + mi * 2048 + cx1);
    const size_t row = bm + wr * 128 + mi * 16 + (lane >> 4) * 4;
#pragma unroll
    for (int ni = 0; ni < 4; ++ni) {
      f32x4 l = {0.f, 0.f, 0.f, 0.f};
      l = __builtin_amdgcn_mfma_f32_16x16x32_bf16(ax0, bl0[ni], l, 0, 0, 0);
      l = __builtin_amdgcn_mfma_f32_16x16x32_bf16(ax1, bl1[ni], l, 0, 0, 0);
      const size_t col = bn + wc * 64 + ni * 16 + (lane & 15);
#pragma unroll
      for (int j = 0; j < 4; ++j)
        out[(row + j) * DOUT + col] = (float)acc[mi][ni][j] * (sc[ni] * tm[mi][j]) + l[j];
    }
  }
}

extern "C" void kernel_launch(void* const* d_in, const int* in_sizes, int n_in,
                              void* d_out, int out_size, void* d_ws, size_t ws_size,
                              hipStream_t stream) {
  const float* x = (const float*)d_in[0];
  const int* qw = (const int*)d_in[1];
  const float* scale = (const float*)d_in[2];
  const float* lA = (const float*)d_in[3];
  const float* lB = (const float*)d_in[4];
  float* out = (float*)d_out;

  char* ws = (char*)d_ws;
  signed char* Xi8 = (signed char*)ws;                              // 33.6 MB
  signed char* Wi8 = (signed char*)(ws + 33554432);                 // 16.8 MB
  __bf16* xa    = (__bf16*)(ws + 50331648);                         // 1.05 MB
  signed char* Ai8 = (signed char*)(ws + 51380224);                 // 0.26 MB
  __bf16* Blt   = (__bf16*)(ws + 51904512);                         // 0.52 MB
  float* tstep  = (float*)(ws + 52428800);                          // 32 KB
  float* astep  = (float*)(ws + 52461568);                          // 256 B

  hipFuncSetAttribute((const void*)gemm_i8_kernel,
                      hipFuncAttributeMaxDynamicSharedMemorySize, 131072);

  quant_x_kernel<<<MTOT, 256, 0, stream>>>(x, Xi8, tstep);
  cvt_w_kernel<<<DOUT * (DIN / 4) / 256, 256, 0, stream>>>(qw, Wi8);
  cvt_ab_kernel<<<320, 256, 0, stream>>>(lA, lB, Ai8, astep, Blt);
  lora_xa_kernel<<<MTOT / 32, 128, 0, stream>>>(Xi8, tstep, Ai8, astep, xa);
  gemm_i8_kernel<<<(MTOT / 256) * (DOUT / 256), 512, 131072, stream>>>(
      Xi8, Wi8, scale, tstep, xa, Blt, out);
}